// Round 6
// baseline (2709.403 us; speedup 1.0000x reference)
//
#include <hip/hip_runtime.h>
#include <stdint.h>

typedef unsigned short ushort_t;
typedef __attribute__((ext_vector_type(4))) float f32x4;
typedef __attribute__((ext_vector_type(8))) short bf16x8;
typedef __attribute__((ext_vector_type(4))) unsigned short u16x4;

#define DEV static __device__ __forceinline__

DEV unsigned short f2bf(float f) {
  unsigned int u = __float_as_uint(f);
  unsigned int r = (u + 0x7fffu + ((u >> 16) & 1u)) >> 16;
  return (unsigned short)r;
}

DEV void async16(const void* g, void* l) {
  __builtin_amdgcn_global_load_lds(
      (const __attribute__((address_space(1))) unsigned int*)g,
      (__attribute__((address_space(3))) unsigned int*)l, 16, 0, 0);
}

// ---------------------------------------------------------------------------
// C = act( [A0|A1][M,K] @ [W0|W1][N,K]^T + bias ), split at K0. bf16 in, f32
// acc. 128x128 tile, BK=32, 4 waves (2x2), 4x4 16x16x32 frags.
// Staging: tile = 128x32 = 4096 elem = 8 wave-calls of 64 lanes x 8 elem
//          -> exactly 2 calls per wave (c in {0,1}).
// C-row remap for batch-strided output: global_row =
//   (mBase/rowsPerBatch)*cBatchStrideRows + cRowOff + mBase%rowsPerBatch + lr
// ---------------------------------------------------------------------------
template<bool SPLIT, bool RELU, bool OUTBF16>
__global__ __launch_bounds__(256, 2)
void gemm_bt(const ushort_t* __restrict__ A0, int lda0,
             const ushort_t* __restrict__ A1, int lda1,
             const ushort_t* __restrict__ W0, int ldw0,
             const ushort_t* __restrict__ W1, int ldw1,
             int K0, int K,
             const float* __restrict__ bias,
             void* __restrict__ Cv, int ldc,
             int rowsPerBatch, int cBatchStrideRows, int cRowOff)
{
  __shared__ __align__(16) ushort_t sA[2][128 * 32];
  __shared__ __align__(16) ushort_t sB[2][128 * 32];

  const int tid = threadIdx.x;
  const int w = tid >> 6, lane = tid & 63;
  const int mBase = blockIdx.y * 128;
  const int nBase = blockIdx.x * 128;
  const int wr = w >> 1, wc = w & 1;

  f32x4 acc[4][4] = {};

  auto stage = [&](int kt, int buf) {
    const int k0 = kt * 32;
    const ushort_t* Ap = A0; int lda = lda0; int ka = k0;
    const ushort_t* Wp = W0; int ldw = ldw0; int kw = k0;
    if (SPLIT && k0 >= K0) {
      Ap = A1; lda = lda1; ka = k0 - K0;
      Wp = W1; ldw = ldw1; kw = k0 - K0;
    }
#pragma unroll
    for (int c = 0; c < 2; ++c) {
      const int eb = (w * 2 + c) * 512;          // wave-uniform LDS element base
      const int e = eb + lane * 8;               // 0..4095
      const int row = e >> 5, col = e & 31;      // row 0..127
      async16(Ap + (size_t)(mBase + row) * lda + (ka + col), &sA[buf][eb]);
    }
#pragma unroll
    for (int c = 0; c < 2; ++c) {
      const int eb = (w * 2 + c) * 512;
      const int e = eb + lane * 8;
      const int row = e >> 5, col = e & 31;
      async16(Wp + (size_t)(nBase + row) * ldw + (kw + col), &sB[buf][eb]);
    }
  };

  const int nkt = K >> 5;
  stage(0, 0);
  int cur = 0;
  const int fr = lane & 15, kg = (lane >> 4) * 8;

  for (int kt = 0; kt < nkt; ++kt) {
    __syncthreads();                     // vmcnt drained before barrier: tile ready
    if (kt + 1 < nkt) stage(kt + 1, cur ^ 1);
    bf16x8 a[4], b[4];
#pragma unroll
    for (int m = 0; m < 4; ++m)
      a[m] = *(const bf16x8*)&sA[cur][(wr * 64 + m * 16 + fr) * 32 + kg];
#pragma unroll
    for (int n = 0; n < 4; ++n)
      b[n] = *(const bf16x8*)&sB[cur][(wc * 64 + n * 16 + fr) * 32 + kg];
#pragma unroll
    for (int m = 0; m < 4; ++m)
#pragma unroll
      for (int n = 0; n < 4; ++n)
        acc[m][n] = __builtin_amdgcn_mfma_f32_16x16x32_bf16(a[m], b[n], acc[m][n], 0, 0, 0);
    cur ^= 1;
  }

  const int bIdx = mBase / rowsPerBatch;
  const int rowBase = bIdx * cBatchStrideRows + cRowOff + (mBase - bIdx * rowsPerBatch);

  float* Cf = (float*)Cv;
  ushort_t* Cb = (ushort_t*)Cv;
  const int q = lane >> 4;
#pragma unroll
  for (int n = 0; n < 4; ++n) {
    const int gcol = nBase + wc * 64 + n * 16 + fr;
    const float bv = bias[gcol];
#pragma unroll
    for (int m = 0; m < 4; ++m) {
      const int lr = wr * 64 + m * 16 + q * 4;
#pragma unroll
      for (int j = 0; j < 4; ++j) {
        float v = acc[m][n][j] + bv;
        if (RELU) v = v > 0.f ? v : 0.01f * v;
        const size_t idx = (size_t)(rowBase + lr + j) * ldc + gcol;
        if (OUTBF16) Cb[idx] = f2bf(v); else Cf[idx] = v;
      }
    }
  }
}

// ---------------------------------------------------------------------------
// Detect whether `start` is int32 {0,1} (mode 0) or byte-packed bool (mode 1).
// Reads 8192 words = 32KB: in-bounds under BOTH interpretations.
// ---------------------------------------------------------------------------
__global__ __launch_bounds__(256)
void detect_mode(const int* __restrict__ start, int* __restrict__ mode) {
  const int tid = threadIdx.x;
  int acc = 0;
  for (int i = tid; i < 8192; i += 256) acc |= start[i];
  __shared__ int red[256];
  red[tid] = acc;
  __syncthreads();
  for (int s = 128; s > 0; s >>= 1) {
    if (tid < s) red[tid] |= red[tid + s];
    __syncthreads();
  }
  if (tid == 0) *mode = (red[0] & ~1) ? 1 : 0;
}

// ---------------------------------------------------------------------------
// Segmented scan over a T-chunk with carry. z packed [8, Tc, 1024] (rows
// b*Tc+t). One thread per (b,g) channel; 8192 channels.
// ---------------------------------------------------------------------------
__global__ __launch_bounds__(256)
void scan_chunk(float* __restrict__ z, const void* __restrict__ start,
                const int* __restrict__ mode, float* __restrict__ carry,
                int first, int t0, int Tc) {
  const int id = blockIdx.x * 256 + threadIdx.x;   // 0..8191
  const int b = id >> 10, g = id & 1023;
  float s = first ? -6.93147180559945f : carry[id];
  float* zp = z + ((size_t)b * Tc) * 1024 + g;
  if (*mode) {
    const signed char* st = (const signed char*)start + (size_t)b * 4096 + t0;
    for (int t = 0; t < Tc; ++t) {
      const float zv = zp[(size_t)t * 1024];
      s = st[t] ? zv : (s + zv);
      zp[(size_t)t * 1024] = s;
    }
  } else {
    const int* st = (const int*)start + (size_t)b * 4096 + t0;
    for (int t = 0; t < Tc; ++t) {
      const float zv = zp[(size_t)t * 1024];
      s = st[t] ? zv : (s + zv);
      zp[(size_t)t * 1024] = s;
    }
  }
  carry[id] = s;
}

// ---------------------------------------------------------------------------
// Row softmax over 1024, f32 in -> bf16 out. One block (256 thr) per row.
// ---------------------------------------------------------------------------
__global__ __launch_bounds__(256)
void softmax_rows(const float* __restrict__ S, ushort_t* __restrict__ P) {
  const int row = blockIdx.x;
  const int tid = threadIdx.x, lane = tid & 63, w = tid >> 6;
  const float4 v = ((const float4*)(S + (size_t)row * 1024))[tid];
  float mx = fmaxf(fmaxf(v.x, v.y), fmaxf(v.z, v.w));
#pragma unroll
  for (int o = 32; o > 0; o >>= 1) mx = fmaxf(mx, __shfl_xor(mx, o));
  __shared__ float smx[4], ssum[4];
  if (lane == 0) smx[w] = mx;
  __syncthreads();
  mx = fmaxf(fmaxf(smx[0], smx[1]), fmaxf(smx[2], smx[3]));
  const float e0 = __expf(v.x - mx), e1 = __expf(v.y - mx);
  const float e2 = __expf(v.z - mx), e3 = __expf(v.w - mx);
  float sum = e0 + e1 + e2 + e3;
#pragma unroll
  for (int o = 32; o > 0; o >>= 1) sum += __shfl_xor(sum, o);
  if (lane == 0) ssum[w] = sum;
  __syncthreads();
  sum = ssum[0] + ssum[1] + ssum[2] + ssum[3];
  const float inv = 1.0f / sum;
  u16x4 o4;
  o4.x = f2bf(e0 * inv); o4.y = f2bf(e1 * inv);
  o4.z = f2bf(e2 * inv); o4.w = f2bf(e3 * inv);
  *(u16x4*)(P + (size_t)row * 1024 + tid * 4) = o4;
}

// ---------------------------------------------------------------------------
// f32 -> bf16 with source row stride. i indexes quads.
// ---------------------------------------------------------------------------
__global__ __launch_bounds__(256)
void cvt_strided(const float* __restrict__ src, int srcStride,
                 ushort_t* __restrict__ dst, int cols, int nq) {
  const int i = blockIdx.x * 256 + threadIdx.x;
  if (i >= nq) return;
  const int colsq = cols >> 2;
  const int row = i / colsq, cq = i - row * colsq;
  const float4 v = *(const float4*)(src + (size_t)row * srcStride + cq * 4);
  u16x4 o;
  o.x = f2bf(v.x); o.y = f2bf(v.y); o.z = f2bf(v.z); o.w = f2bf(v.w);
  *(u16x4*)(dst + (size_t)row * cols + cq * 4) = o;
}

// ---------------------------------------------------------------------------
// Pack x[b, t0..t0+Tc, 0:256] -> dst [8*Tc, 256] bf16.  nq = 8*Tc*64 quads.
// ---------------------------------------------------------------------------
__global__ __launch_bounds__(256)
void cvt_x_chunk(const float* __restrict__ x, ushort_t* __restrict__ dst,
                 int t0, int tcShift, int nq) {
  const int i = blockIdx.x * 256 + threadIdx.x;
  if (i >= nq) return;
  const int row = i >> 6, cq = i & 63;
  const int b = row >> tcShift, tl = row & ((1 << tcShift) - 1);
  const float4 v = *(const float4*)(x + ((size_t)b * 4096 + t0 + tl) * 256 + cq * 4);
  u16x4 o;
  o.x = f2bf(v.x); o.y = f2bf(v.y); o.z = f2bf(v.z); o.w = f2bf(v.w);
  *(u16x4*)(dst + (size_t)row * 256 + cq * 4) = o;
}

// ---------------------------------------------------------------------------
// Weight folding: Wout[g,0:256] = bf16( sum_h A[g,h]*Wi[h,0:256] )
//                 bias_out[g]   = bias_in[g] + sum_h A[g,h]*bi[h]
// ---------------------------------------------------------------------------
__global__ __launch_bounds__(256)
void fold_win(const float* __restrict__ A, int ldA,
              const float* __restrict__ Wi, const float* __restrict__ bi,
              const float* __restrict__ bias_in,
              ushort_t* __restrict__ Wout, float* __restrict__ bias_out) {
  const int g = blockIdx.x, d = threadIdx.x;
  float acc = 0.f, bacc = 0.f;
  const float* Arow = A + (size_t)g * ldA;
  for (int h = 0; h < 1024; ++h)
    acc += Arow[h] * Wi[(size_t)h * 256 + d];
  for (int h = d; h < 1024; h += 256) bacc += Arow[h] * bi[h];
  __shared__ float red[256];
  red[d] = bacc;
  __syncthreads();
  for (int s = 128; s > 0; s >>= 1) {
    if (d < s) red[d] += red[d + s];
    __syncthreads();
  }
  Wout[(size_t)g * 256 + d] = f2bf(acc);
  if (d == 0) bias_out[g] = bias_in[g] + red[0];
}

// ---------------------------------------------------------------------------
__global__ __launch_bounds__(256)
void fill_diag(float* __restrict__ out, int n, float v) {
  const int i = blockIdx.x * 256 + threadIdx.x;
  if (i < n) out[i] = v;
}

// ---------------------------------------------------------------------------
extern "C" void kernel_launch(void* const* d_in, const int* in_sizes, int n_in,
                              void* d_out, int out_size, void* d_ws, size_t ws_size,
                              hipStream_t stream) {
  const float* x    = (const float*)d_in[0];
  const void* start = (const void*)d_in[1];
  const float* Wi   = (const float*)d_in[2];
  const float* bi   = (const float*)d_in[3];
  const float* Wp   = (const float*)d_in[4];
  const float* bp   = (const float*)d_in[5];
  const float* Wf   = (const float*)d_in[6];
  const float* bf_  = (const float*)d_in[7];
  const float* Wo   = (const float*)d_in[8];
  const float* bo   = (const float*)d_in[9];

  const int T = 4096, H = 1024;

  char* ws = (char*)d_ws;
  size_t off = 0;
  auto alloc = [&](size_t bytes) {
    char* p = ws + off; off += (bytes + 255) & ~(size_t)255; return p;
  };

  // --- fixed region: folded/converted weights + carries + mode (~8.2 MB) ---
  ushort_t* wz0  = (ushort_t*)alloc((size_t)H * 256 * 2);
  ushort_t* wc0  = (ushort_t*)alloc((size_t)H * 256 * 2);
  ushort_t* wc1  = (ushort_t*)alloc((size_t)H * 256 * 2);
  ushort_t* wp1  = (ushort_t*)alloc((size_t)H * H * 2);
  ushort_t* wf0a = (ushort_t*)alloc((size_t)H * H * 2);
  ushort_t* wf1a = (ushort_t*)alloc((size_t)H * H * 2);
  ushort_t* wob  = (ushort_t*)alloc((size_t)256 * H * 2);
  float* bz0 = (float*)alloc(H * 4);
  float* bc0 = (float*)alloc(H * 4);
  float* bc1 = (float*)alloc(H * 4);
  float* carry0 = (float*)alloc(8192 * 4);
  float* carry1 = (float*)alloc(8192 * 4);
  int* mode = (int*)alloc(256);
  const size_t fixed = off;

  // --- choose largest fitting T-chunk ---
  auto chunkBytes = [&](int Tc) -> size_t {
    const size_t Mc = (size_t)8 * Tc;
    return Mc * 256 * 2 + 256 +   // xbc
           Mc * H * 4   + 256 +   // zbuf
           Mc * H * 2   + 256 +   // pbuf
           Mc * H * 2   + 256;    // hbuf
  };
  int Tc = 4096;
  while (Tc > 128 && fixed + chunkBytes(Tc) > ws_size) Tc >>= 1;
  if (fixed + chunkBytes(Tc) > ws_size) {
    fill_diag<<<dim3((out_size + 255) / 256), dim3(256), 0, stream>>>(
        (float*)d_out, out_size, (float)(ws_size >> 20));
    return;
  }
  const int Mc = 8 * Tc;
  const int tcShift = __builtin_ctz((unsigned)Tc);
  ushort_t* xbc = (ushort_t*)alloc((size_t)Mc * 256 * 2);
  float*    zbuf = (float*)alloc((size_t)Mc * H * 4);
  ushort_t* pbuf = (ushort_t*)alloc((size_t)Mc * H * 2);
  ushort_t* hbuf = (ushort_t*)alloc((size_t)Mc * H * 2);

  const dim3 blk(256);

  // --- weight prep ---
  cvt_strided<<<dim3((H * 256 + 255) / 256), blk, 0, stream>>>(
      Wp + (size_t)H * H, H, wp1, H, H * 256);
  cvt_strided<<<dim3((H * 256 + 255) / 256), blk, 0, stream>>>(
      Wf, 2 * H, wf0a, H, H * 256);
  cvt_strided<<<dim3((H * 256 + 255) / 256), blk, 0, stream>>>(
      Wf + (size_t)H * 2 * H, 2 * H, wf1a, H, H * 256);
  cvt_strided<<<dim3((256 * 256 + 255) / 256), blk, 0, stream>>>(
      Wo, H, wob, H, 256 * 256);
  fold_win<<<dim3(H), blk, 0, stream>>>(Wp, H, Wi, bi, bp, wz0, bz0);
  fold_win<<<dim3(H), blk, 0, stream>>>(Wf + H, 2 * H, Wi, bi, bf_, wc0, bc0);
  fold_win<<<dim3(H), blk, 0, stream>>>(Wf + (size_t)H * 2 * H + H, 2 * H, Wi, bi,
                                        bf_ + H, wc1, bc1);
  detect_mode<<<dim3(1), blk, 0, stream>>>((const int*)start, mode);

  // --- chunked pipeline ---
  const int nch = T / Tc;
  for (int c = 0; c < nch; ++c) {
    const int t0 = c * Tc;
    cvt_x_chunk<<<dim3((Mc * 64 + 255) / 256), blk, 0, stream>>>(
        x, xbc, t0, tcShift, Mc * 64);
    // z0 = x @ (Wp0·Wi)^T + (bp0 + Wp0·bi)
    gemm_bt<false, false, false><<<dim3(H / 128, Mc / 128), blk, 0, stream>>>(
        xbc, 256, xbc, 256, wz0, 256, wz0, 256, 256, 256, bz0, zbuf, H, Mc, 0, 0);
    scan_chunk<<<dim3(32), blk, 0, stream>>>(zbuf, start, mode, carry0, c == 0, t0, Tc);
    softmax_rows<<<dim3(Mc), blk, 0, stream>>>(zbuf, pbuf);
    // h0 = leaky( p @ Wf0a^T + x @ (WfB0·Wi)^T + bc0 )
    gemm_bt<true, true, true><<<dim3(H / 128, Mc / 128), blk, 0, stream>>>(
        pbuf, H, xbc, 256, wf0a, H, wc0, 256, H, H + 256, bc0, hbuf, H, Mc, 0, 0);
    // z1 = h0 @ Wp1^T + bp1
    gemm_bt<false, false, false><<<dim3(H / 128, Mc / 128), blk, 0, stream>>>(
        hbuf, H, hbuf, H, wp1, H, wp1, H, H, H, bp + H, zbuf, H, Mc, 0, 0);
    scan_chunk<<<dim3(32), blk, 0, stream>>>(zbuf, start, mode, carry1, c == 0, t0, Tc);
    softmax_rows<<<dim3(Mc), blk, 0, stream>>>(zbuf, pbuf);
    // h1 = leaky( p @ Wf1a^T + x @ (WfB1·Wi)^T + bc1 )
    gemm_bt<true, true, true><<<dim3(H / 128, Mc / 128), blk, 0, stream>>>(
        pbuf, H, xbc, 256, wf1a, H, wc1, 256, H, H + 256, bc1, hbuf, H, Mc, 0, 0);
    // out = h1 @ Wo^T + bo  (batch-strided C write into d_out)
    gemm_bt<false, false, false><<<dim3(256 / 128, Mc / 128), blk, 0, stream>>>(
        hbuf, H, hbuf, H, wob, H, wob, H, H, H, bo, (float*)d_out, 256,
        Tc, T, t0);
  }
}

// Round 7
// 932.935 us; speedup vs baseline: 2.9042x; 2.9042x over previous
//
#include <hip/hip_runtime.h>
#include <stdint.h>

typedef unsigned short ushort_t;
typedef __attribute__((ext_vector_type(4))) float f32x4;
typedef __attribute__((ext_vector_type(8))) short bf16x8;
typedef __attribute__((ext_vector_type(4))) unsigned short u16x4;

#define DEV static __device__ __forceinline__

DEV unsigned short f2bf(float f) {
  unsigned int u = __float_as_uint(f);
  unsigned int r = (u + 0x7fffu + ((u >> 16) & 1u)) >> 16;
  return (unsigned short)r;
}

DEV void async16(const void* g, void* l) {
  __builtin_amdgcn_global_load_lds(
      (const __attribute__((address_space(1))) unsigned int*)g,
      (__attribute__((address_space(3))) unsigned int*)l, 16, 0, 0);
}

// ---------------------------------------------------------------------------
// C = act( [A0|A1][M,K] @ [W0|W1][N,K]^T + bias ), split at K0. bf16 in, f32
// acc. 128x128 tile, BK=32, 4 waves (2x2), 4x4 16x16x32 frags.
// Staging: tile = 128x32 = 4096 elem = 2 wave-calls per wave (c in {0,1}).
// ---------------------------------------------------------------------------
template<bool SPLIT, bool RELU, bool OUTBF16>
__global__ __launch_bounds__(256, 2)
void gemm_bt(const ushort_t* __restrict__ A0, int lda0,
             const ushort_t* __restrict__ A1, int lda1,
             const ushort_t* __restrict__ W0, int ldw0,
             const ushort_t* __restrict__ W1, int ldw1,
             int K0, int K,
             const float* __restrict__ bias,
             void* __restrict__ Cv, int ldc,
             int rowsPerBatch, int cBatchStrideRows, int cRowOff)
{
  __shared__ __align__(16) ushort_t sA[2][128 * 32];
  __shared__ __align__(16) ushort_t sB[2][128 * 32];

  const int tid = threadIdx.x;
  const int w = tid >> 6, lane = tid & 63;
  const int mBase = blockIdx.y * 128;
  const int nBase = blockIdx.x * 128;
  const int wr = w >> 1, wc = w & 1;

  f32x4 acc[4][4] = {};

  auto stage = [&](int kt, int buf) {
    const int k0 = kt * 32;
    const ushort_t* Ap = A0; int lda = lda0; int ka = k0;
    const ushort_t* Wp = W0; int ldw = ldw0; int kw = k0;
    if (SPLIT && k0 >= K0) {
      Ap = A1; lda = lda1; ka = k0 - K0;
      Wp = W1; ldw = ldw1; kw = k0 - K0;
    }
#pragma unroll
    for (int c = 0; c < 2; ++c) {
      const int eb = (w * 2 + c) * 512;          // wave-uniform LDS element base
      const int e = eb + lane * 8;               // 0..4095
      const int row = e >> 5, col = e & 31;      // row 0..127
      async16(Ap + (size_t)(mBase + row) * lda + (ka + col), &sA[buf][eb]);
    }
#pragma unroll
    for (int c = 0; c < 2; ++c) {
      const int eb = (w * 2 + c) * 512;
      const int e = eb + lane * 8;
      const int row = e >> 5, col = e & 31;
      async16(Wp + (size_t)(nBase + row) * ldw + (kw + col), &sB[buf][eb]);
    }
  };

  const int nkt = K >> 5;
  stage(0, 0);
  int cur = 0;
  const int fr = lane & 15, kg = (lane >> 4) * 8;

  for (int kt = 0; kt < nkt; ++kt) {
    __syncthreads();                     // vmcnt drained before barrier: tile ready
    if (kt + 1 < nkt) stage(kt + 1, cur ^ 1);
    bf16x8 a[4], b[4];
#pragma unroll
    for (int m = 0; m < 4; ++m)
      a[m] = *(const bf16x8*)&sA[cur][(wr * 64 + m * 16 + fr) * 32 + kg];
#pragma unroll
    for (int n = 0; n < 4; ++n)
      b[n] = *(const bf16x8*)&sB[cur][(wc * 64 + n * 16 + fr) * 32 + kg];
#pragma unroll
    for (int m = 0; m < 4; ++m)
#pragma unroll
      for (int n = 0; n < 4; ++n)
        acc[m][n] = __builtin_amdgcn_mfma_f32_16x16x32_bf16(a[m], b[n], acc[m][n], 0, 0, 0);
    cur ^= 1;
  }

  const int bIdx = mBase / rowsPerBatch;
  const int rowBase = bIdx * cBatchStrideRows + cRowOff + (mBase - bIdx * rowsPerBatch);

  float* Cf = (float*)Cv;
  ushort_t* Cb = (ushort_t*)Cv;
  const int q = lane >> 4;
#pragma unroll
  for (int n = 0; n < 4; ++n) {
    const int gcol = nBase + wc * 64 + n * 16 + fr;
    const float bv = bias[gcol];
#pragma unroll
    for (int m = 0; m < 4; ++m) {
      const int lr = wr * 64 + m * 16 + q * 4;
#pragma unroll
      for (int j = 0; j < 4; ++j) {
        float v = acc[m][n][j] + bv;
        if (RELU) v = v > 0.f ? v : 0.01f * v;
        const size_t idx = (size_t)(rowBase + lr + j) * ldc + gcol;
        if (OUTBF16) Cb[idx] = f2bf(v); else Cf[idx] = v;
      }
    }
  }
}

// ---------------------------------------------------------------------------
// Detect whether `start` is int32 {0,1} (mode 0) or byte-packed bool (mode 1).
// ---------------------------------------------------------------------------
__global__ __launch_bounds__(256)
void detect_mode(const int* __restrict__ start, int* __restrict__ mode) {
  const int tid = threadIdx.x;
  int acc = 0;
  for (int i = tid; i < 8192; i += 256) acc |= start[i];
  __shared__ int red[256];
  red[tid] = acc;
  __syncthreads();
  for (int s = 128; s > 0; s >>= 1) {
    if (tid < s) red[tid] |= red[tid + s];
    __syncthreads();
  }
  if (tid == 0) *mode = (red[0] & ~1) ? 1 : 0;
}

DEV int start_at(const void* start, int m, size_t idx) {
  return m ? (int)((const signed char*)start)[idx] : ((const int*)start)[idx];
}

// ---------------------------------------------------------------------------
// Parallel segmented scan, 3 phases. z packed [8, Tc, 1024]; T-blocks of 128.
// Monoid: (s,f) o (sig,phi) = (phi ? sig : s+sig, f|phi), identity (0,false).
// ---------------------------------------------------------------------------
// P1: per (b, g, tb): local fold -> aggS[(b*NT+tb)*1024+g]; aggF[b*NT+tb].
__global__ __launch_bounds__(256)
void scan_p1(const float* __restrict__ z, const void* __restrict__ start,
             const int* __restrict__ mode, float* __restrict__ aggS,
             int* __restrict__ aggF, int t0, int Tc, int NT) {
  const int id = blockIdx.x * 256 + threadIdx.x;
  const int g = id & 1023;
  const int r = id >> 10;                 // 0 .. 8*NT-1
  const int b = r / NT, tb = r - b * NT;
  const int m = *mode;
  const size_t sbase = (size_t)b * 4096 + t0 + tb * 128;
  const float* zp = z + ((size_t)b * Tc + tb * 128) * 1024 + g;
  float ls = 0.f;
  int lf = 0;
  for (int t = 0; t < 128; ++t) {
    const float zv = zp[(size_t)t * 1024];
    const int st = start_at(start, m, sbase + t);
    ls = st ? zv : (ls + zv);
    lf |= st;
  }
  aggS[(size_t)r * 1024 + g] = ls;
  if (g == 0) aggF[r] = lf;
}

// P2: per (b,g): scan NT aggregates -> prefixS (state before each block),
//     update carry (state after chunk).
__global__ __launch_bounds__(256)
void scan_p2(const float* __restrict__ aggS, const int* __restrict__ aggF,
             float* __restrict__ prefixS, float* __restrict__ carry,
             int first, int NT) {
  const int id = blockIdx.x * 256 + threadIdx.x;   // 0..8191
  const int b = id >> 10, g = id & 1023;
  float s = first ? -6.93147180559945f : carry[id];
  for (int tb = 0; tb < NT; ++tb) {
    const size_t r = (size_t)(b * NT + tb);
    prefixS[r * 1024 + g] = s;
    const float sum = aggS[r * 1024 + g];
    s = aggF[r] ? sum : (s + sum);
  }
  carry[id] = s;
}

// P3: per (b, g, tb): seed from prefix, rescan block, write states in place.
__global__ __launch_bounds__(256)
void scan_p3(float* __restrict__ z, const void* __restrict__ start,
             const int* __restrict__ mode, const float* __restrict__ prefixS,
             int t0, int Tc, int NT) {
  const int id = blockIdx.x * 256 + threadIdx.x;
  const int g = id & 1023;
  const int r = id >> 10;
  const int b = r / NT, tb = r - b * NT;
  const int m = *mode;
  const size_t sbase = (size_t)b * 4096 + t0 + tb * 128;
  float* zp = z + ((size_t)b * Tc + tb * 128) * 1024 + g;
  float s = prefixS[(size_t)r * 1024 + g];
  for (int t = 0; t < 128; ++t) {
    const float zv = zp[(size_t)t * 1024];
    const int st = start_at(start, m, sbase + t);
    s = st ? zv : (s + zv);
    zp[(size_t)t * 1024] = s;
  }
}

// ---------------------------------------------------------------------------
// Row softmax over 1024, f32 in -> bf16 out. One block (256 thr) per row.
// ---------------------------------------------------------------------------
__global__ __launch_bounds__(256)
void softmax_rows(const float* __restrict__ S, ushort_t* __restrict__ P) {
  const int row = blockIdx.x;
  const int tid = threadIdx.x, lane = tid & 63, w = tid >> 6;
  const float4 v = ((const float4*)(S + (size_t)row * 1024))[tid];
  float mx = fmaxf(fmaxf(v.x, v.y), fmaxf(v.z, v.w));
#pragma unroll
  for (int o = 32; o > 0; o >>= 1) mx = fmaxf(mx, __shfl_xor(mx, o));
  __shared__ float smx[4], ssum[4];
  if (lane == 0) smx[w] = mx;
  __syncthreads();
  mx = fmaxf(fmaxf(smx[0], smx[1]), fmaxf(smx[2], smx[3]));
  const float e0 = __expf(v.x - mx), e1 = __expf(v.y - mx);
  const float e2 = __expf(v.z - mx), e3 = __expf(v.w - mx);
  float sum = e0 + e1 + e2 + e3;
#pragma unroll
  for (int o = 32; o > 0; o >>= 1) sum += __shfl_xor(sum, o);
  if (lane == 0) ssum[w] = sum;
  __syncthreads();
  sum = ssum[0] + ssum[1] + ssum[2] + ssum[3];
  const float inv = 1.0f / sum;
  u16x4 o4;
  o4.x = f2bf(e0 * inv); o4.y = f2bf(e1 * inv);
  o4.z = f2bf(e2 * inv); o4.w = f2bf(e3 * inv);
  *(u16x4*)(P + (size_t)row * 1024 + tid * 4) = o4;
}

// ---------------------------------------------------------------------------
// f32 -> bf16 with source row stride. i indexes quads.
// ---------------------------------------------------------------------------
__global__ __launch_bounds__(256)
void cvt_strided(const float* __restrict__ src, int srcStride,
                 ushort_t* __restrict__ dst, int cols, int nq) {
  const int i = blockIdx.x * 256 + threadIdx.x;
  if (i >= nq) return;
  const int colsq = cols >> 2;
  const int row = i / colsq, cq = i - row * colsq;
  const float4 v = *(const float4*)(src + (size_t)row * srcStride + cq * 4);
  u16x4 o;
  o.x = f2bf(v.x); o.y = f2bf(v.y); o.z = f2bf(v.z); o.w = f2bf(v.w);
  *(u16x4*)(dst + (size_t)row * cols + cq * 4) = o;
}

// ---------------------------------------------------------------------------
// Pack x[b, t0..t0+Tc, 0:256] -> dst [8*Tc, 256] bf16.  nq = 8*Tc*64 quads.
// ---------------------------------------------------------------------------
__global__ __launch_bounds__(256)
void cvt_x_chunk(const float* __restrict__ x, ushort_t* __restrict__ dst,
                 int t0, int tcShift, int nq) {
  const int i = blockIdx.x * 256 + threadIdx.x;
  if (i >= nq) return;
  const int row = i >> 6, cq = i & 63;
  const int b = row >> tcShift, tl = row & ((1 << tcShift) - 1);
  const float4 v = *(const float4*)(x + ((size_t)b * 4096 + t0 + tl) * 256 + cq * 4);
  u16x4 o;
  o.x = f2bf(v.x); o.y = f2bf(v.y); o.z = f2bf(v.z); o.w = f2bf(v.w);
  *(u16x4*)(dst + (size_t)row * 256 + cq * 4) = o;
}

// ---------------------------------------------------------------------------
// Weight folding: Wout[g,0:256] = bf16( sum_h A[g,h]*Wi[h,0:256] )
//                 bias_out[g]   = bias_in[g] + sum_h A[g,h]*bi[h]
// ---------------------------------------------------------------------------
__global__ __launch_bounds__(256)
void fold_win(const float* __restrict__ A, int ldA,
              const float* __restrict__ Wi, const float* __restrict__ bi,
              const float* __restrict__ bias_in,
              ushort_t* __restrict__ Wout, float* __restrict__ bias_out) {
  const int g = blockIdx.x, d = threadIdx.x;
  float acc = 0.f, bacc = 0.f;
  const float* Arow = A + (size_t)g * ldA;
  for (int h = 0; h < 1024; ++h)
    acc += Arow[h] * Wi[(size_t)h * 256 + d];
  for (int h = d; h < 1024; h += 256) bacc += Arow[h] * bi[h];
  __shared__ float red[256];
  red[d] = bacc;
  __syncthreads();
  for (int s = 128; s > 0; s >>= 1) {
    if (d < s) red[d] += red[d + s];
    __syncthreads();
  }
  Wout[(size_t)g * 256 + d] = f2bf(acc);
  if (d == 0) bias_out[g] = bias_in[g] + red[0];
}

// ---------------------------------------------------------------------------
__global__ __launch_bounds__(256)
void fill_diag(float* __restrict__ out, int n, float v) {
  const int i = blockIdx.x * 256 + threadIdx.x;
  if (i < n) out[i] = v;
}

// ---------------------------------------------------------------------------
extern "C" void kernel_launch(void* const* d_in, const int* in_sizes, int n_in,
                              void* d_out, int out_size, void* d_ws, size_t ws_size,
                              hipStream_t stream) {
  const float* x    = (const float*)d_in[0];
  const void* start = (const void*)d_in[1];
  const float* Wi   = (const float*)d_in[2];
  const float* bi   = (const float*)d_in[3];
  const float* Wp   = (const float*)d_in[4];
  const float* bp   = (const float*)d_in[5];
  const float* Wf   = (const float*)d_in[6];
  const float* bf_  = (const float*)d_in[7];
  const float* Wo   = (const float*)d_in[8];
  const float* bo   = (const float*)d_in[9];

  const int T = 4096, H = 1024;

  char* ws = (char*)d_ws;
  size_t off = 0;
  auto alloc = [&](size_t bytes) {
    char* p = ws + off; off += (bytes + 255) & ~(size_t)255; return p;
  };

  // --- fixed region: folded weights + scan scratch (~10.3 MB) ---
  ushort_t* wz0  = (ushort_t*)alloc((size_t)H * 256 * 2);
  ushort_t* wc0  = (ushort_t*)alloc((size_t)H * 256 * 2);
  ushort_t* wc1  = (ushort_t*)alloc((size_t)H * 256 * 2);
  ushort_t* wp1  = (ushort_t*)alloc((size_t)H * H * 2);
  ushort_t* wf0a = (ushort_t*)alloc((size_t)H * H * 2);
  ushort_t* wf1a = (ushort_t*)alloc((size_t)H * H * 2);
  ushort_t* wob  = (ushort_t*)alloc((size_t)256 * H * 2);
  float* bz0 = (float*)alloc(H * 4);
  float* bc0 = (float*)alloc(H * 4);
  float* bc1 = (float*)alloc(H * 4);
  float* carry0 = (float*)alloc(8192 * 4);
  float* carry1 = (float*)alloc(8192 * 4);
  int* mode = (int*)alloc(256);
  float* aggS    = (float*)alloc((size_t)8 * 32 * 1024 * 4);   // 1 MB (NT<=32)
  float* prefixS = (float*)alloc((size_t)8 * 32 * 1024 * 4);   // 1 MB
  int*   aggF    = (int*)alloc(8 * 32 * 4);
  const size_t fixed = off;

  // --- choose largest fitting T-chunk (>=128 so NT=Tc/128>=1) ---
  auto chunkBytes = [&](int Tc) -> size_t {
    const size_t Mc = (size_t)8 * Tc;
    return Mc * 256 * 2 + 256 + Mc * H * 4 + 256 +
           Mc * H * 2 + 256 + Mc * H * 2 + 256;
  };
  int Tc = 4096;
  while (Tc > 128 && fixed + chunkBytes(Tc) > ws_size) Tc >>= 1;
  if (fixed + chunkBytes(Tc) > ws_size) {
    fill_diag<<<dim3((out_size + 255) / 256), dim3(256), 0, stream>>>(
        (float*)d_out, out_size, (float)(ws_size >> 20));
    return;
  }
  const int Mc = 8 * Tc;
  const int NT = Tc / 128;
  const int tcShift = __builtin_ctz((unsigned)Tc);
  ushort_t* xbc = (ushort_t*)alloc((size_t)Mc * 256 * 2);
  float*    zbuf = (float*)alloc((size_t)Mc * H * 4);
  ushort_t* pbuf = (ushort_t*)alloc((size_t)Mc * H * 2);
  ushort_t* hbuf = (ushort_t*)alloc((size_t)Mc * H * 2);

  const dim3 blk(256);
  const dim3 scanGrid(32 * NT);

  auto run_scan = [&](float* z, float* carry, int first, int t0) {
    scan_p1<<<scanGrid, blk, 0, stream>>>(z, start, mode, aggS, aggF, t0, Tc, NT);
    scan_p2<<<dim3(32), blk, 0, stream>>>(aggS, aggF, prefixS, carry, first, NT);
    scan_p3<<<scanGrid, blk, 0, stream>>>(z, start, mode, prefixS, t0, Tc, NT);
  };

  // --- weight prep ---
  cvt_strided<<<dim3((H * 256 + 255) / 256), blk, 0, stream>>>(
      Wp + (size_t)H * H, H, wp1, H, H * 256);
  cvt_strided<<<dim3((H * 256 + 255) / 256), blk, 0, stream>>>(
      Wf, 2 * H, wf0a, H, H * 256);
  cvt_strided<<<dim3((H * 256 + 255) / 256), blk, 0, stream>>>(
      Wf + (size_t)H * 2 * H, 2 * H, wf1a, H, H * 256);
  cvt_strided<<<dim3((256 * 256 + 255) / 256), blk, 0, stream>>>(
      Wo, H, wob, H, 256 * 256);
  fold_win<<<dim3(H), blk, 0, stream>>>(Wp, H, Wi, bi, bp, wz0, bz0);
  fold_win<<<dim3(H), blk, 0, stream>>>(Wf + H, 2 * H, Wi, bi, bf_, wc0, bc0);
  fold_win<<<dim3(H), blk, 0, stream>>>(Wf + (size_t)H * 2 * H + H, 2 * H, Wi, bi,
                                        bf_ + H, wc1, bc1);
  detect_mode<<<dim3(1), blk, 0, stream>>>((const int*)start, mode);

  // --- chunked pipeline (Tc=4096 -> single chunk) ---
  const int nch = T / Tc;
  for (int c = 0; c < nch; ++c) {
    const int t0 = c * Tc;
    cvt_x_chunk<<<dim3((Mc * 64 + 255) / 256), blk, 0, stream>>>(
        x, xbc, t0, tcShift, Mc * 64);
    // z0 = x @ (Wp0·Wi)^T + (bp0 + Wp0·bi)
    gemm_bt<false, false, false><<<dim3(H / 128, Mc / 128), blk, 0, stream>>>(
        xbc, 256, xbc, 256, wz0, 256, wz0, 256, 256, 256, bz0, zbuf, H, Mc, 0, 0);
    run_scan(zbuf, carry0, c == 0, t0);
    softmax_rows<<<dim3(Mc), blk, 0, stream>>>(zbuf, pbuf);
    // h0 = leaky( p @ Wf0a^T + x @ (WfB0·Wi)^T + bc0 )
    gemm_bt<true, true, true><<<dim3(H / 128, Mc / 128), blk, 0, stream>>>(
        pbuf, H, xbc, 256, wf0a, H, wc0, 256, H, H + 256, bc0, hbuf, H, Mc, 0, 0);
    // z1 = h0 @ Wp1^T + bp1
    gemm_bt<false, false, false><<<dim3(H / 128, Mc / 128), blk, 0, stream>>>(
        hbuf, H, hbuf, H, wp1, H, wp1, H, H, H, bp + H, zbuf, H, Mc, 0, 0);
    run_scan(zbuf, carry1, c == 0, t0);
    softmax_rows<<<dim3(Mc), blk, 0, stream>>>(zbuf, pbuf);
    // h1 = leaky( p @ Wf1a^T + x @ (WfB1·Wi)^T + bc1 )
    gemm_bt<true, true, true><<<dim3(H / 128, Mc / 128), blk, 0, stream>>>(
        pbuf, H, xbc, 256, wf1a, H, wc1, 256, H, H + 256, bc1, hbuf, H, Mc, 0, 0);
    // out = h1 @ Wo^T + bo  (batch-strided C write into d_out)
    gemm_bt<false, false, false><<<dim3(256 / 128, Mc / 128), blk, 0, stream>>>(
        hbuf, H, hbuf, H, wob, H, wob, H, H, H, bo, (float*)d_out, 256,
        Tc, T, t0);
  }
}